// Round 9
// baseline (330.605 us; speedup 1.0000x reference)
//
#include <hip/hip_runtime.h>
#include <hip/hip_bf16.h>
#include <hip/hip_cooperative_groups.h>

namespace cg = cooperative_groups;

typedef __hip_bfloat16 bf16;
typedef __attribute__((ext_vector_type(8))) short short8;
typedef __attribute__((ext_vector_type(4))) float floatx4;

#define DEVI __device__ __forceinline__

DEVI float b2f(bf16 v) { return __bfloat162float(v); }
DEVI bf16 f2b(float v) { return __float2bfloat16(v); }
DEVI unsigned short f2bu(float v) {
    bf16 h = __float2bfloat16(v);
    unsigned short u;
    __builtin_memcpy(&u, &h, 2);
    return u;
}
DEVI float sigmoidf_(float z) { return 1.0f / (1.0f + __expf(-z)); }

// Problem constants
// B=8, H=W=56, C=192, WS=4 -> 14x14 windows, 1568 rows (=49*32), ind=3072,
// hid=ncl=256.  ALL inputs/outputs are float32.
//
// MFMA fragment conventions (mfma_f32_16x16x32_bf16, verified R2-R8):
//   A[m][k]: lane = quad*16 + m15 -> m = m15, k = quad*8 + j  (16B contiguous)
//   B[k][n]: lane = quad*16 + n15 -> k = quad*8 + j, n = n15
//   D[m][n]: col n = lane&15, row m = quad*4 + reg
//
// Key algebraic identities used (all ref-checked through R8, absmax 0.0039):
//   sigmoid(L) > 0.5  <=>  L > 0      (tm literals need only logit signs)
//   clause = AND over included literals of (lit > 0.5)   (min>tau <=> all>tau)
//   feat = sigmoid(clauses @ (vote_w@W2/16) + b2)        (logits not an output)
//
// R9: single persistent cooperative kernel; phases separated by grid.sync():
//   P0: ln_win (6272) + w1frag (384) + vw2 (768) + inc_mask (16)  [7440 units]
//   P1: gemm1 8-way K-split MFMA                                  [784 units]
//   P2: tm (bitwise clause eval)                                  [1568 units]
//   P3: gemm2 + window-reverse + roll + gated residual            [1176 units]

__global__ void mega_kernel(const float* __restrict__ x,
                            const float* __restrict__ gamma,
                            const float* __restrict__ beta,
                            const float* __restrict__ W1,
                            const float* __restrict__ b1,
                            const float* __restrict__ inc_w,
                            const float* __restrict__ vote_w,
                            const float* __restrict__ W2,
                            const float* __restrict__ b2v,
                            const float* __restrict__ gate,
                            bf16* __restrict__ win,
                            float* __restrict__ part,
                            unsigned short* __restrict__ w1frag,
                            unsigned short* __restrict__ vw2frag,
                            bf16* __restrict__ clauses_bf,
                            unsigned* __restrict__ mask,
                            float* __restrict__ out,
                            float* __restrict__ cl_out,
                            float* __restrict__ sum_out) {
    cg::grid_group gg = cg::this_grid();
    __shared__ unsigned g_s[16];
    __shared__ float red[4];

    const int t = threadIdx.x;
    const int wave = t >> 6;
    const int lane = t & 63;
    const int quad = lane >> 4;
    const int l15 = lane & 15;
    const unsigned gsz = gridDim.x;

    // ================= P0: ln_win + w1frag + vw2 + inc_mask =================
    for (unsigned u = blockIdx.x; u < 7440u; u += gsz) {
        if (u < 6272u) {
            // ---- LayerNorm + roll(-2,-2) + window partition (1 px / wave) ----
            int blk = (int)u * 4 + wave;  // b*3136 + h'*56 + w' (rolled coords)
            int w_ = blk % 56;
            int t2 = blk / 56;
            int h_ = t2 % 56;
            int b = t2 / 56;
            int hs = h_ + 2; if (hs >= 56) hs -= 56;
            int ws = w_ + 2; if (ws >= 56) ws -= 56;
            const float* xp = x + (((b * 56 + hs) * 56 + ws) * 192);
            float v0 = xp[lane];
            float v1 = xp[lane + 64];
            float v2 = xp[lane + 128];
            float s = v0 + v1 + v2;
            float sq = v0 * v0 + v1 * v1 + v2 * v2;
#pragma unroll
            for (int m = 1; m < 64; m <<= 1) {
                s += __shfl_xor(s, m, 64);
                sq += __shfl_xor(sq, m, 64);
            }
            float mean = s * (1.0f / 192.0f);
            float var = sq * (1.0f / 192.0f) - mean * mean;
            float inv = rsqrtf(var + 1e-5f);
            int row = b * 196 + (h_ >> 2) * 14 + (w_ >> 2);
            int fb = ((h_ & 3) * 4 + (w_ & 3)) * 192;
            bf16* wp = win + row * 3072 + fb;
            wp[lane]       = f2b((v0 - mean) * inv * gamma[lane]       + beta[lane]);
            wp[lane + 64]  = f2b((v1 - mean) * inv * gamma[lane + 64]  + beta[lane + 64]);
            wp[lane + 128] = f2b((v2 - mean) * inv * gamma[lane + 128] + beta[lane + 128]);
        } else if (u < 6656u) {
            // ---- W1 repack: one 1KB fragment per wave, coalesced stores ----
            int bid = (int)u - 6272;       // 0..383
            int fid = bid * 4 + wave;      // = nb*96 + kb
            int nb = fid / 96;
            int kb = fid - nb * 96;
            int n = nb * 16 + l15;
            int k = kb * 32 + quad * 8;
            short8 v;
#pragma unroll
            for (int j = 0; j < 8; j++) {
                v[j] = (short)f2bu(W1[(k + j) * 256 + n]);
            }
            *reinterpret_cast<short8*>(w1frag + ((size_t)fid * 64 + lane) * 8) = v;
        } else if (u < 7424u) {
            // ---- vw2 MFMA: M=256(k_out), N=3072, K=192 ----
            int bid = (int)u - 6656;       // 0..767
            int mt = bid & 15;             // 16-wide k_out tile
            int nt = (bid >> 4) * 4 + wave; // 0..191: 16-wide n tile

            const float* ap = vote_w + (mt * 16 + l15) * 192 + quad * 8;
            const float* bp = W2 + (quad * 8) * 3072 + nt * 16 + l15;

            floatx4 acc = {0.f, 0.f, 0.f, 0.f};
#pragma unroll
            for (int kb = 0; kb < 6; kb++) {
                float4 a0 = *reinterpret_cast<const float4*>(ap + kb * 32);
                float4 a1 = *reinterpret_cast<const float4*>(ap + kb * 32 + 4);
                short8 a, b;
                a[0] = (short)f2bu(a0.x); a[1] = (short)f2bu(a0.y);
                a[2] = (short)f2bu(a0.z); a[3] = (short)f2bu(a0.w);
                a[4] = (short)f2bu(a1.x); a[5] = (short)f2bu(a1.y);
                a[6] = (short)f2bu(a1.z); a[7] = (short)f2bu(a1.w);
#pragma unroll
                for (int j = 0; j < 8; j++) {
                    b[j] = (short)f2bu(bp[(kb * 32 + j) * 3072]);
                }
                acc = __builtin_amdgcn_mfma_f32_16x16x32_bf16(a, b, acc, 0, 0, 0);
            }
#pragma unroll
            for (int r = 0; r < 4; r++) {
                int k = mt * 16 + quad * 4 + r;  // gemm2 k index (0..255)
                int off = ((nt * 8 + (k >> 5)) * 64 + ((k >> 3) & 3) * 16 + l15) * 8 + (k & 7);
                vw2frag[off] = f2bu(acc[r] * 0.0625f);  // 1/sqrt(256)
            }
        } else {
            // ---- inc bitmask: mask[word(16)][clause(256)] ----
            int wi = (int)u - 7424;        // 0..15
            unsigned bits = 0u;
            int base = t * 512 + wi * 32;
#pragma unroll
            for (int b = 0; b < 32; b++) {
                if (inc_w[base + b] > 0.0f) bits |= (1u << b);
            }
            mask[wi * 256 + t] = bits;
        }
    }
    gg.sync();

    // ================= P1: gemm1 raw logit partials (8-way K-split) ==========
    // M=1568, N=256, K=3072.  4 waves = 2m x 2n; wave tile 16m x 64n (4 acc).
    for (unsigned u = blockIdx.x; u < 784u; u += gsz) {
        int kz = (int)u / 98;              // 0..7
        int rest = (int)u - kz * 98;
        int ny = rest / 49;                // 0..1
        int mx = rest - ny * 49;           // 0..48
        int wm = wave & 1;
        int wn = wave >> 1;
        int m0 = mx * 32 + wm * 16;
        int nb0 = ny * 8 + wn * 4;         // 16-wide n-tile base (0..15)

        const bf16* ap = win + (m0 + l15) * 3072 + kz * 384 + quad * 8;
        const unsigned short* bp = w1frag + lane * 8;
        int kb0 = kz * 12;

        floatx4 acc[4];
#pragma unroll
        for (int i = 0; i < 4; i++) acc[i] = (floatx4){0.f, 0.f, 0.f, 0.f};

#pragma unroll 4
        for (int kb = 0; kb < 12; kb++) {
            short8 a = *reinterpret_cast<const short8*>(ap + kb * 32);
#pragma unroll
            for (int i = 0; i < 4; i++) {
                short8 b = *reinterpret_cast<const short8*>(
                    bp + ((size_t)((nb0 + i) * 96 + kb0 + kb)) * 512);
                acc[i] = __builtin_amdgcn_mfma_f32_16x16x32_bf16(a, b, acc[i], 0, 0, 0);
            }
        }

        float* pp = part + kz * 401408;
#pragma unroll
        for (int i = 0; i < 4; i++) {
            int n_g = (nb0 + i) * 16 + l15;
#pragma unroll
            for (int r = 0; r < 4; r++) {
                int m_g = m0 + quad * 4 + r;
                pp[m_g * 256 + n_g] = acc[i][r];
            }
        }
    }
    gg.sync();

    // ================= P2: tm bitwise clause eval ===========================
    for (unsigned u = blockIdx.x; u < 1568u; u += gsz) {
        int row = (int)u;
        int idx = row * 256 + t;
        float L = b1[t];
#pragma unroll
        for (int s = 0; s < 8; s++) L += part[s * 401408 + idx];
        unsigned long long bhi = __ballot(L > 0.0f);  // lit t
        unsigned long long blo = __ballot(L < 0.0f);  // lit 256+t
        if (lane == 0) {
            g_s[wave * 2]         = (unsigned)bhi;
            g_s[wave * 2 + 1]     = (unsigned)(bhi >> 32);
            g_s[8 + wave * 2]     = (unsigned)blo;
            g_s[8 + wave * 2 + 1] = (unsigned)(blo >> 32);
        }
        __syncthreads();
        unsigned ok = 1u;
#pragma unroll
        for (int w = 0; w < 16; w++) {
            unsigned viol = (~g_s[w]) & mask[w * 256 + t];
            ok &= (viol == 0u) ? 1u : 0u;
        }
        float hard = (float)ok;
        cl_out[idx] = hard;
        clauses_bf[idx] = f2b(hard);
        unsigned long long cb = __ballot(ok != 0u);
        if (lane == 0) red[wave] = (float)__popcll(cb);
        __syncthreads();
        if (t == 0) sum_out[row] = (red[0] + red[1] + red[2] + red[3]) * (1.0f / 256.0f);
        __syncthreads();  // protect g_s/red across persistent-loop iterations
    }
    gg.sync();

    // ================= P3: gemm2 + window-reverse + roll + gated residual ===
    float g = sigmoidf_(gate[0]);
    for (unsigned u = blockIdx.x; u < 1176u; u += gsz) {
        int mx = (int)u % 49;
        int ncol = (int)u / 49;            // 0..23
        int wm = wave & 1;
        int wn = wave >> 1;
        int m0 = mx * 32 + wm * 16;
        int nb0 = ncol * 8 + wn * 4;       // 16-wide n-tile base (0..191)

        const bf16* ap = clauses_bf + (m0 + l15) * 256 + quad * 8;
        const unsigned short* bp = vw2frag + lane * 8;

        floatx4 acc[4];
#pragma unroll
        for (int i = 0; i < 4; i++) acc[i] = (floatx4){0.f, 0.f, 0.f, 0.f};

#pragma unroll
        for (int kb = 0; kb < 8; kb++) {
            short8 a = *reinterpret_cast<const short8*>(ap + kb * 32);
#pragma unroll
            for (int i = 0; i < 4; i++) {
                short8 b = *reinterpret_cast<const short8*>(
                    bp + ((size_t)((nb0 + i) * 8 + kb)) * 512);
                acc[i] = __builtin_amdgcn_mfma_f32_16x16x32_bf16(a, b, acc[i], 0, 0, 0);
            }
        }

        // per-r inverse window mapping: m_g -> (batch, window-h, window-w)
        int bq[4], wh[4], ww[4];
#pragma unroll
        for (int r = 0; r < 4; r++) {
            int m_g = m0 + quad * 4 + r;
            bq[r] = m_g / 196;
            int rem = m_g - bq[r] * 196;
            wh[r] = rem / 14;
            ww[r] = rem - wh[r] * 14;
        }
#pragma unroll
        for (int i = 0; i < 4; i++) {
            int n_g = (nb0 + i) * 16 + l15;
            int cell = n_g / 192;           // 0..15 (position inside 4x4 window)
            int ch = n_g - cell * 192;      // channel
            int cellh = cell >> 2;
            int cellw = cell & 3;
            float bb = b2v[n_g];
#pragma unroll
            for (int r = 0; r < 4; r++) {
                int hh = wh[r] * 4 + cellh + 2; if (hh >= 56) hh -= 56;  // roll(+2)
                int wc = ww[r] * 4 + cellw + 2; if (wc >= 56) wc -= 56;
                int gid = ((bq[r] * 56 + hh) * 56 + wc) * 192 + ch;
                float mv = sigmoidf_(acc[i][r] + bb);
                out[gid] = x[gid] + g * mv + (1.0f - g) * sigmoidf_(mv);
            }
        }
    }
}

// ---------------------------------------------------------------------------
extern "C" void kernel_launch(void* const* d_in, const int* in_sizes, int n_in,
                              void* d_out, int out_size, void* d_ws, size_t ws_size,
                              hipStream_t stream) {
    const float* x      = (const float*)d_in[0];
    const float* gamma  = (const float*)d_in[1];
    const float* beta   = (const float*)d_in[2];
    const float* W1     = (const float*)d_in[3];
    const float* b1     = (const float*)d_in[4];
    const float* inc_w  = (const float*)d_in[5];
    const float* vote_w = (const float*)d_in[6];
    const float* W2     = (const float*)d_in[7];
    const float* b2v    = (const float*)d_in[8];
    const float* gate   = (const float*)d_in[9];

    char* ws = (char*)d_ws;
    // workspace carve (bytes), total ~26.4 MB:
    bf16*           win        = (bf16*)(ws + 0);                  // 9,633,792
    float*          part       = (float*)(ws + 9633792);           // 12,845,056 (8x 1568*256*4)
    unsigned short* w1frag     = (unsigned short*)(ws + 22478848); // 1,572,864
    unsigned short* vw2frag    = (unsigned short*)(ws + 24051712); // 1,572,864
    bf16*           clauses_bf = (bf16*)(ws + 25624576);           //   802,816
    unsigned*       mask       = (unsigned*)(ws + 26427392);       //    16,384

    float* out     = (float*)d_out;
    float* cl_out  = out + 4816896;            // clauses: 1568*256
    float* sum_out = cl_out + 401408;          // summary: 1568

    // Cooperative grid: exactly the resident capacity (persistent blocks).
    int nb = 0;
    hipOccupancyMaxActiveBlocksPerMultiprocessor(&nb, mega_kernel, 256, 0);
    if (nb < 1) nb = 1;
    unsigned grid = (unsigned)nb * 256u;   // 256 CUs on MI355X
    if (grid > 7440u) grid = 7440u;

    void* args[] = {(void*)&x, (void*)&gamma, (void*)&beta, (void*)&W1, (void*)&b1,
                    (void*)&inc_w, (void*)&vote_w, (void*)&W2, (void*)&b2v, (void*)&gate,
                    (void*)&win, (void*)&part, (void*)&w1frag, (void*)&vw2frag,
                    (void*)&clauses_bf, (void*)&mask,
                    (void*)&out, (void*)&cl_out, (void*)&sum_out};
    hipLaunchCooperativeKernel(mega_kernel, dim3(grid), dim3(256), args, 0, stream);
}

// Round 10
// 143.605 us; speedup vs baseline: 2.3022x; 2.3022x over previous
//
#include <hip/hip_runtime.h>
#include <hip/hip_bf16.h>

typedef __hip_bfloat16 bf16;
typedef __attribute__((ext_vector_type(8))) short short8;
typedef __attribute__((ext_vector_type(4))) float floatx4;

#define DEVI __device__ __forceinline__

DEVI float b2f(bf16 v) { return __bfloat162float(v); }
DEVI bf16 f2b(float v) { return __float2bfloat16(v); }
DEVI unsigned short f2bu(float v) {
    bf16 h = __float2bfloat16(v);
    unsigned short u;
    __builtin_memcpy(&u, &h, 2);
    return u;
}
DEVI float sigmoidf_(float z) { return 1.0f / (1.0f + __expf(-z)); }

// Problem constants
// B=8, H=W=56, C=192, WS=4 -> 14x14 windows, 1568 rows (=49*32), ind=3072,
// hid=ncl=256.  ALL inputs/outputs are float32.
//
// MFMA fragment conventions (mfma_f32_16x16x32_bf16, verified R2-R8):
//   A[m][k]: lane = quad*16 + m15 -> m = m15, k = quad*8 + j  (16B contiguous)
//   B[k][n]: lane = quad*16 + n15 -> k = quad*8 + j, n = n15
//   D[m][n]: col n = lane&15, row m = quad*4 + reg
//
// Key algebraic identities (ref-checked through R8, absmax 0.0039):
//   sigmoid(L) > 0.5  <=>  L > 0      (tm literals need only logit signs)
//   clause = AND over included literals of (lit > 0.5)   (min>tau <=> all>tau)
//   feat = sigmoid(clauses @ (vote_w@W2/16) + b2)        (logits not an output)
//
// R10 structure = R7 (best known, 139.6) + win-1x gemm1 + bf16 part + 4px ln:
//   K1: ln_win(1568,4px/wave) + w1frag(384) + vw2(768) + inc_mask(16)
//   K2: gemm1 (49,8) x 512thr, 8-way K-split, win read once
//   K3: tm (bitwise clause eval, bf16 partials)
//   K4: gemm2 + window-reverse + roll + gated residual

// ---------------------------------------------------------------------------
__global__ __launch_bounds__(256) void k1_pre(const float* __restrict__ x,
                                              const float* __restrict__ gamma,
                                              const float* __restrict__ beta,
                                              const float* __restrict__ W1,
                                              const float* __restrict__ vote_w,
                                              const float* __restrict__ W2,
                                              const float* __restrict__ inc_w,
                                              bf16* __restrict__ win,
                                              unsigned short* __restrict__ w1frag,
                                              unsigned short* __restrict__ vw2frag,
                                              unsigned* __restrict__ mask) {
    unsigned u = blockIdx.x;
    int t = threadIdx.x;
    int wave = t >> 6;
    int lane = t & 63;
    int quad = lane >> 4;
    int l15 = lane & 15;
    if (u < 1568u) {
        // ---- LayerNorm + roll(-2,-2) + window partition: 4 pixels per wave ----
        int blk0 = (int)u * 16 + wave * 4;
        const float* xp[4];
        int row[4], fb[4];
#pragma unroll
        for (int pi = 0; pi < 4; pi++) {
            int blk = blk0 + pi;       // b*3136 + h'*56 + w'  (rolled coords)
            int w_ = blk % 56;
            int t2 = blk / 56;
            int h_ = t2 % 56;
            int b = t2 / 56;
            int hs = h_ + 2; if (hs >= 56) hs -= 56;
            int ws = w_ + 2; if (ws >= 56) ws -= 56;
            xp[pi] = x + (((b * 56 + hs) * 56 + ws) * 192);
            row[pi] = b * 196 + (h_ >> 2) * 14 + (w_ >> 2);
            fb[pi] = ((h_ & 3) * 4 + (w_ & 3)) * 192;
        }
        float v[4][3];
#pragma unroll
        for (int pi = 0; pi < 4; pi++) {
            v[pi][0] = xp[pi][lane];
            v[pi][1] = xp[pi][lane + 64];
            v[pi][2] = xp[pi][lane + 128];
        }
        float g0 = gamma[lane], g1 = gamma[lane + 64], g2 = gamma[lane + 128];
        float e0 = beta[lane],  e1 = beta[lane + 64],  e2 = beta[lane + 128];
#pragma unroll
        for (int pi = 0; pi < 4; pi++) {
            float s = v[pi][0] + v[pi][1] + v[pi][2];
            float sq = v[pi][0] * v[pi][0] + v[pi][1] * v[pi][1] + v[pi][2] * v[pi][2];
#pragma unroll
            for (int m = 1; m < 64; m <<= 1) {
                s += __shfl_xor(s, m, 64);
                sq += __shfl_xor(sq, m, 64);
            }
            float mean = s * (1.0f / 192.0f);
            float var = sq * (1.0f / 192.0f) - mean * mean;
            float inv = rsqrtf(var + 1e-5f);
            bf16* wp = win + row[pi] * 3072 + fb[pi];
            wp[lane]       = f2b((v[pi][0] - mean) * inv * g0 + e0);
            wp[lane + 64]  = f2b((v[pi][1] - mean) * inv * g1 + e1);
            wp[lane + 128] = f2b((v[pi][2] - mean) * inv * g2 + e2);
        }
    } else if (u < 1952u) {
        // ---- W1 repack: one 1KB fragment per wave, coalesced 16B/lane stores ----
        int bid = (int)u - 1568;       // 0..383
        int fid = bid * 4 + wave;      // = nb*96 + kb
        int nb = fid / 96;
        int kb = fid - nb * 96;
        int n = nb * 16 + l15;
        int k = kb * 32 + quad * 8;
        short8 v;
#pragma unroll
        for (int j = 0; j < 8; j++) {
            v[j] = (short)f2bu(W1[(k + j) * 256 + n]);
        }
        *reinterpret_cast<short8*>(w1frag + ((size_t)fid * 64 + lane) * 8) = v;
    } else if (u < 2720u) {
        // ---- vw2 MFMA: M=256(k_out), N=3072, K=192 -> bf16 B-frag ----
        int bid = (int)u - 1952;       // 0..767
        int mt = bid & 15;             // 16-wide k_out tile
        int nt = (bid >> 4) * 4 + wave; // 0..191: 16-wide n tile

        const float* ap = vote_w + (mt * 16 + l15) * 192 + quad * 8;
        const float* bp = W2 + (quad * 8) * 3072 + nt * 16 + l15;

        floatx4 acc = {0.f, 0.f, 0.f, 0.f};
#pragma unroll
        for (int kb = 0; kb < 6; kb++) {
            float4 a0 = *reinterpret_cast<const float4*>(ap + kb * 32);
            float4 a1 = *reinterpret_cast<const float4*>(ap + kb * 32 + 4);
            short8 a, b;
            a[0] = (short)f2bu(a0.x); a[1] = (short)f2bu(a0.y);
            a[2] = (short)f2bu(a0.z); a[3] = (short)f2bu(a0.w);
            a[4] = (short)f2bu(a1.x); a[5] = (short)f2bu(a1.y);
            a[6] = (short)f2bu(a1.z); a[7] = (short)f2bu(a1.w);
#pragma unroll
            for (int j = 0; j < 8; j++) {
                b[j] = (short)f2bu(bp[(kb * 32 + j) * 3072]);
            }
            acc = __builtin_amdgcn_mfma_f32_16x16x32_bf16(a, b, acc, 0, 0, 0);
        }
#pragma unroll
        for (int r = 0; r < 4; r++) {
            int k = mt * 16 + quad * 4 + r;  // gemm2 k index (0..255)
            int off = ((nt * 8 + (k >> 5)) * 64 + ((k >> 3) & 3) * 16 + l15) * 8 + (k & 7);
            vw2frag[off] = f2bu(acc[r] * 0.0625f);  // 1/sqrt(256)
        }
    } else {
        // ---- inc bitmask: mask[word(16)][clause(256)] ----
        int wi = (int)u - 2720;        // 0..15
        unsigned bits = 0u;
        int base = t * 512 + wi * 32;
#pragma unroll
        for (int b = 0; b < 32; b++) {
            if (inc_w[base + b] > 0.0f) bits |= (1u << b);
        }
        mask[wi * 256 + t] = bits;
    }
}

// ---------------------------------------------------------------------------
// K2: raw logit partials of win @ W1 (bf16 out).  M=1568, N=256, K=3072,
// 8-way K-split.  512-thread blocks: 8 waves = 2mh x 4wn; block tile
// 32m x 256n x 384k -> win read ONCE; grid (49, 8) = 392 blocks (12 waves/CU).
__global__ __launch_bounds__(512) void gemm1_mfma(const bf16* __restrict__ win,
                                                  const unsigned short* __restrict__ w1frag,
                                                  unsigned short* __restrict__ partb) {
    int t = threadIdx.x;
    int wave = t >> 6;
    int lane = t & 63;
    int quad = lane >> 4;
    int l15 = lane & 15;
    int mh = wave & 1;
    int wn = wave >> 1;                // 0..3
    int m0 = blockIdx.x * 32 + mh * 16;
    int nb0 = wn * 4;                  // 16-wide n-tile base (0..15)
    int kz = blockIdx.y;               // 0..7, k in [kz*384, kz*384+384)

    const bf16* ap = win + (m0 + l15) * 3072 + kz * 384 + quad * 8;
    const unsigned short* bp = w1frag + lane * 8;
    int kb0 = kz * 12;

    floatx4 acc[4];
#pragma unroll
    for (int i = 0; i < 4; i++) acc[i] = (floatx4){0.f, 0.f, 0.f, 0.f};

#pragma unroll 4
    for (int kb = 0; kb < 12; kb++) {
        short8 a = *reinterpret_cast<const short8*>(ap + kb * 32);
#pragma unroll
        for (int i = 0; i < 4; i++) {
            short8 b = *reinterpret_cast<const short8*>(
                bp + ((size_t)((nb0 + i) * 96 + kb0 + kb)) * 512);
            acc[i] = __builtin_amdgcn_mfma_f32_16x16x32_bf16(a, b, acc[i], 0, 0, 0);
        }
    }

    unsigned short* pp = partb + (size_t)kz * 401408;
#pragma unroll
    for (int i = 0; i < 4; i++) {
        int n_g = (nb0 + i) * 16 + l15;
#pragma unroll
        for (int r = 0; r < 4; r++) {
            int m_g = m0 + quad * 4 + r;
            pp[m_g * 256 + n_g] = f2bu(acc[i][r]);
        }
    }
}

// ---------------------------------------------------------------------------
// K3: clauses via bitwise AND over logit signs.  One block per window row.
// lit t included-true  <=> logit > 0;  lit 256+t  <=> logit < 0.
__global__ __launch_bounds__(256) void tm_kernel(const unsigned short* __restrict__ partb,
                                                 const float* __restrict__ b1,
                                                 const unsigned* __restrict__ mask,
                                                 float* __restrict__ cl_out,
                                                 bf16* __restrict__ clauses_bf,
                                                 float* __restrict__ sum_out) {
    __shared__ unsigned g_s[16];
    __shared__ float red[4];
    int row = blockIdx.x;
    int t = threadIdx.x;
    int wave = t >> 6;
    int lane = t & 63;
    int idx = row * 256 + t;
    float L = b1[t];
#pragma unroll
    for (int s = 0; s < 8; s++) {
        unsigned short u = partb[(size_t)s * 401408 + idx];
        bf16 h;
        __builtin_memcpy(&h, &u, 2);
        L += b2f(h);
    }
    unsigned long long bhi = __ballot(L > 0.0f);  // lit t
    unsigned long long blo = __ballot(L < 0.0f);  // lit 256+t
    if (lane == 0) {
        g_s[wave * 2]         = (unsigned)bhi;
        g_s[wave * 2 + 1]     = (unsigned)(bhi >> 32);
        g_s[8 + wave * 2]     = (unsigned)blo;
        g_s[8 + wave * 2 + 1] = (unsigned)(blo >> 32);
    }
    __syncthreads();
    unsigned ok = 1u;
#pragma unroll
    for (int w = 0; w < 16; w++) {
        unsigned viol = (~g_s[w]) & mask[w * 256 + t];
        ok &= (viol == 0u) ? 1u : 0u;
    }
    float hard = (float)ok;
    cl_out[idx] = hard;
    clauses_bf[idx] = f2b(hard);
    unsigned long long cb = __ballot(ok != 0u);
    if (lane == 0) red[wave] = (float)__popcll(cb);
    __syncthreads();
    if (t == 0) sum_out[row] = (red[0] + red[1] + red[2] + red[3]) * (1.0f / 256.0f);
}

// ---------------------------------------------------------------------------
// K4: fused  feat = sigmoid(clauses @ vw2 + b2)  +  window-reverse + roll(+2,+2)
// + gated residual -> out.  M=1568, N=3072, K=256.  grid (49, 24), 4 waves
// 2m x 2n, wave tile 16m x 64n (4 acc tiles).  feat never materialized.
__global__ __launch_bounds__(256) void gemm2_out(const bf16* __restrict__ clauses_bf,
                                                 const unsigned short* __restrict__ vw2frag,
                                                 const float* __restrict__ b2v,
                                                 const float* __restrict__ x,
                                                 const float* __restrict__ gate,
                                                 float* __restrict__ out) {
    int t = threadIdx.x;
    int wave = t >> 6;
    int lane = t & 63;
    int quad = lane >> 4;
    int mlo = lane & 15;
    int wm = wave & 1;
    int wn = wave >> 1;
    int m0 = blockIdx.x * 32 + wm * 16;
    int nb0 = blockIdx.y * 8 + wn * 4;  // 16-wide n-tile base (0..191)

    const bf16* ap = clauses_bf + (m0 + mlo) * 256 + quad * 8;
    const unsigned short* bp = vw2frag + lane * 8;

    floatx4 acc[4];
#pragma unroll
    for (int i = 0; i < 4; i++) acc[i] = (floatx4){0.f, 0.f, 0.f, 0.f};

#pragma unroll
    for (int kb = 0; kb < 8; kb++) {
        short8 a = *reinterpret_cast<const short8*>(ap + kb * 32);
#pragma unroll
        for (int i = 0; i < 4; i++) {
            short8 b = *reinterpret_cast<const short8*>(
                bp + ((size_t)((nb0 + i) * 8 + kb)) * 512);
            acc[i] = __builtin_amdgcn_mfma_f32_16x16x32_bf16(a, b, acc[i], 0, 0, 0);
        }
    }

    float g = sigmoidf_(gate[0]);
    // per-r inverse window mapping: m_g -> (batch, window-h, window-w)
    int bq[4], wh[4], ww[4];
#pragma unroll
    for (int r = 0; r < 4; r++) {
        int m_g = m0 + quad * 4 + r;
        bq[r] = m_g / 196;
        int rem = m_g - bq[r] * 196;
        wh[r] = rem / 14;
        ww[r] = rem - wh[r] * 14;
    }
#pragma unroll
    for (int i = 0; i < 4; i++) {
        int n_g = (nb0 + i) * 16 + mlo;
        int cell = n_g / 192;           // 0..15 (position inside 4x4 window)
        int ch = n_g - cell * 192;      // channel
        int cellh = cell >> 2;
        int cellw = cell & 3;
        float bb = b2v[n_g];
#pragma unroll
        for (int r = 0; r < 4; r++) {
            int hh = wh[r] * 4 + cellh + 2; if (hh >= 56) hh -= 56;  // roll(+2)
            int wc = ww[r] * 4 + cellw + 2; if (wc >= 56) wc -= 56;
            int gid = ((bq[r] * 56 + hh) * 56 + wc) * 192 + ch;
            float mv = sigmoidf_(acc[i][r] + bb);
            out[gid] = x[gid] + g * mv + (1.0f - g) * sigmoidf_(mv);
        }
    }
}

// ---------------------------------------------------------------------------
extern "C" void kernel_launch(void* const* d_in, const int* in_sizes, int n_in,
                              void* d_out, int out_size, void* d_ws, size_t ws_size,
                              hipStream_t stream) {
    const float* x      = (const float*)d_in[0];
    const float* gamma  = (const float*)d_in[1];
    const float* beta   = (const float*)d_in[2];
    const float* W1     = (const float*)d_in[3];
    const float* b1     = (const float*)d_in[4];
    const float* inc_w  = (const float*)d_in[5];
    const float* vote_w = (const float*)d_in[6];
    const float* W2     = (const float*)d_in[7];
    const float* b2v    = (const float*)d_in[8];
    const float* gate   = (const float*)d_in[9];

    char* ws = (char*)d_ws;
    // workspace carve (bytes), total ~20.0 MB:
    bf16*           win        = (bf16*)(ws + 0);                  // 9,633,792
    unsigned short* partb      = (unsigned short*)(ws + 9633792);  // 6,422,528 (8x 1568*256*2)
    unsigned short* w1frag     = (unsigned short*)(ws + 16056320); // 1,572,864
    unsigned short* vw2frag    = (unsigned short*)(ws + 17629184); // 1,572,864
    bf16*           clauses_bf = (bf16*)(ws + 19202048);           //   802,816
    unsigned*       mask       = (unsigned*)(ws + 20004864);       //    16,384

    float* out     = (float*)d_out;
    float* cl_out  = out + 4816896;            // clauses: 1568*256
    float* sum_out = cl_out + 401408;          // summary: 1568

    k1_pre<<<2736, 256, 0, stream>>>(x, gamma, beta, W1, vote_w, W2, inc_w,
                                     win, w1frag, vw2frag, mask);
    gemm1_mfma<<<dim3(49, 8), 512, 0, stream>>>(win, w1frag, partb);
    tm_kernel<<<1568, 256, 0, stream>>>(partb, b1, mask, cl_out, clauses_bf, sum_out);
    gemm2_out<<<dim3(49, 24), 256, 0, stream>>>(clauses_bf, vw2frag, b2v, x, gate, out);
}

// Round 11
// 139.694 us; speedup vs baseline: 2.3666x; 1.0280x over previous
//
#include <hip/hip_runtime.h>
#include <hip/hip_bf16.h>

typedef __hip_bfloat16 bf16;
typedef __attribute__((ext_vector_type(8))) short short8;
typedef __attribute__((ext_vector_type(4))) float floatx4;

#define DEVI __device__ __forceinline__

DEVI float b2f(bf16 v) { return __bfloat162float(v); }
DEVI bf16 f2b(float v) { return __float2bfloat16(v); }
DEVI unsigned short f2bu(float v) {
    bf16 h = __float2bfloat16(v);
    unsigned short u;
    __builtin_memcpy(&u, &h, 2);
    return u;
}
DEVI float sigmoidf_(float z) { return 1.0f / (1.0f + __expf(-z)); }

// Problem constants
// B=8, H=W=56, C=192, WS=4 -> 14x14 windows, 1568 rows (=49*32), ind=3072,
// hid=ncl=256.  ALL inputs/outputs are float32.
//
// MFMA fragment conventions (mfma_f32_16x16x32_bf16, verified R2-R10):
//   A[m][k]: lane = quad*16 + m15 -> m = m15, k = quad*8 + j  (16B contiguous)
//   B[k][n]: lane = quad*16 + n15 -> k = quad*8 + j, n = n15
//   D[m][n]: col n = lane&15, row m = quad*4 + reg
//
// Key algebraic identities (ref-checked, absmax 0.0039):
//   sigmoid(L) > 0.5  <=>  L > 0      (tm literals need only logit signs)
//   clause = AND over included literals of (lit > 0.5)   (min>tau <=> all>tau)
//   feat = sigmoid(clauses @ (vote_w@W2/16) + b2)        (logits not an output)
//
// R11 = R7 structure (best known, 139.6 us) + D-native partial layout:
//   gemm1 stores partials as float4 [slice][tile(1568)][lane(64)][r(4)]
//   tm: one block per (m-tile, quad) = 4 rows; float4 loads, 4 ballots.
//   Both sides of the gemm1->tm interface are 128B-line perfect.

// ---------------------------------------------------------------------------
// K1: [0,6272) LayerNorm + roll(-2,-2) + window partition -> win (bf16)
//     [6272,6656) W1 f32 -> bf16 B-fragment repack -> w1frag
__global__ __launch_bounds__(256) void k1_lnwin_w1frag(const float* __restrict__ x,
                                                       const float* __restrict__ gamma,
                                                       const float* __restrict__ beta,
                                                       const float* __restrict__ W1,
                                                       bf16* __restrict__ win,
                                                       unsigned short* __restrict__ w1frag) {
    int bx = blockIdx.x;
    int t = threadIdx.x;
    if (bx < 6272) {
        // ---- LayerNorm + shift + window partition (1 pixel per wave) ----
        int blk = bx * 4 + (t >> 6);  // b*3136 + h'*56 + w'  (rolled coords)
        int w_ = blk % 56;
        int t2 = blk / 56;
        int h_ = t2 % 56;
        int b = t2 / 56;
        int hs = h_ + 2; if (hs >= 56) hs -= 56;
        int ws = w_ + 2; if (ws >= 56) ws -= 56;
        const float* xp = x + (((b * 56 + hs) * 56 + ws) * 192);
        int l = t & 63;
        float v0 = xp[l];
        float v1 = xp[l + 64];
        float v2 = xp[l + 128];
        float s = v0 + v1 + v2;
        float sq = v0 * v0 + v1 * v1 + v2 * v2;
#pragma unroll
        for (int m = 1; m < 64; m <<= 1) {
            s += __shfl_xor(s, m, 64);
            sq += __shfl_xor(sq, m, 64);
        }
        float mean = s * (1.0f / 192.0f);
        float var = sq * (1.0f / 192.0f) - mean * mean;
        float inv = rsqrtf(var + 1e-5f);
        int row = b * 196 + (h_ >> 2) * 14 + (w_ >> 2);
        int fb = ((h_ & 3) * 4 + (w_ & 3)) * 192;
        bf16* wp = win + row * 3072 + fb;
        wp[l]       = f2b((v0 - mean) * inv * gamma[l]       + beta[l]);
        wp[l + 64]  = f2b((v1 - mean) * inv * gamma[l + 64]  + beta[l + 64]);
        wp[l + 128] = f2b((v2 - mean) * inv * gamma[l + 128] + beta[l + 128]);
    } else {
        // ---- W1 repack: one 1KB fragment per wave, coalesced 16B/lane stores ----
        int bid = bx - 6272;           // 0..383
        int lane = t & 63;
        int fid = bid * 4 + (t >> 6);  // = nb*96 + kb
        int nb = fid / 96;
        int kb = fid - nb * 96;
        int n = nb * 16 + (lane & 15);
        int k = kb * 32 + (lane >> 4) * 8;
        short8 v;
#pragma unroll
        for (int j = 0; j < 8; j++) {
            v[j] = (short)f2bu(W1[(k + j) * 256 + n]);
        }
        *reinterpret_cast<short8*>(w1frag + ((size_t)fid * 64 + lane) * 8) = v;
    }
}

// ---------------------------------------------------------------------------
// K2: [0,784)     gemm1: raw logit partials of win @ W1 (8-way K-split MFMA)
//     [784,1552)  vw2 = vote_w @ W2 / 16 via MFMA -> vw2frag (bf16 B-frag)
//     [1552,1568) inc bitmask -> mask[word(16)][clause(256)]
// Partials stored D-native: part[kz][tile_lin(1568)][lane(64)][r(4)] as float4.
__global__ __launch_bounds__(256) void k2_gemm1_vw2_mask(const bf16* __restrict__ win,
                                                         const unsigned short* __restrict__ w1frag,
                                                         const float* __restrict__ vote_w,
                                                         const float* __restrict__ W2,
                                                         const float* __restrict__ inc_w,
                                                         float* __restrict__ part,
                                                         unsigned short* __restrict__ vw2frag,
                                                         unsigned* __restrict__ mask) {
    int bx = blockIdx.x;
    int t = threadIdx.x;
    int wave = t >> 6;
    int lane = t & 63;
    int quad = lane >> 4;
    int l15 = lane & 15;
    if (bx < 784) {
        // ---- gemm1: M=1568, N=256, K=3072, 8-way K-split.
        // 4 waves = 2m x 2n; wave tile 16m x 64n (4 acc) -> 1.25 loads/MFMA.
        int kz = bx / 98;              // 0..7
        int rest = bx - kz * 98;
        int ny = rest / 49;            // 0..1
        int mx = rest - ny * 49;       // 0..48
        int wm = wave & 1;
        int wn = wave >> 1;
        int m0 = mx * 32 + wm * 16;
        int nb0 = ny * 8 + wn * 4;     // 16-wide n-tile base (0..15)

        const bf16* ap = win + (m0 + l15) * 3072 + kz * 384 + quad * 8;
        const unsigned short* bp = w1frag + lane * 8;
        int kb0 = kz * 12;

        floatx4 acc[4];
#pragma unroll
        for (int i = 0; i < 4; i++) acc[i] = (floatx4){0.f, 0.f, 0.f, 0.f};

#pragma unroll 4
        for (int kb = 0; kb < 12; kb++) {
            short8 a = *reinterpret_cast<const short8*>(ap + kb * 32);
#pragma unroll
            for (int i = 0; i < 4; i++) {
                short8 b = *reinterpret_cast<const short8*>(
                    bp + ((size_t)((nb0 + i) * 96 + kb0 + kb)) * 512);
                acc[i] = __builtin_amdgcn_mfma_f32_16x16x32_bf16(a, b, acc[i], 0, 0, 0);
            }
        }

        // D-native store: one float4 per acc tile (fully coalesced 1KB/wave).
        int mtile = m0 >> 4;           // 0..97
        float* pp = part + (size_t)kz * 401408;
#pragma unroll
        for (int i = 0; i < 4; i++) {
            int tile_lin = mtile * 16 + (nb0 + i);   // 0..1567
            *reinterpret_cast<float4*>(pp + (size_t)tile_lin * 256 + lane * 4) =
                make_float4(acc[i][0], acc[i][1], acc[i][2], acc[i][3]);
        }
    } else if (bx < 1552) {
        // ---- vw2 MFMA: M=256(k_out), N=3072, K=192 ----
        int bid = bx - 784;            // 0..767
        int mt = bid & 15;             // 16-wide k_out tile
        int nt = (bid >> 4) * 4 + wave; // 0..191: 16-wide n tile

        const float* ap = vote_w + (mt * 16 + l15) * 192 + quad * 8;
        const float* bp = W2 + (quad * 8) * 3072 + nt * 16 + l15;

        floatx4 acc = {0.f, 0.f, 0.f, 0.f};
#pragma unroll
        for (int kb = 0; kb < 6; kb++) {
            float4 a0 = *reinterpret_cast<const float4*>(ap + kb * 32);
            float4 a1 = *reinterpret_cast<const float4*>(ap + kb * 32 + 4);
            short8 a, b;
            a[0] = (short)f2bu(a0.x); a[1] = (short)f2bu(a0.y);
            a[2] = (short)f2bu(a0.z); a[3] = (short)f2bu(a0.w);
            a[4] = (short)f2bu(a1.x); a[5] = (short)f2bu(a1.y);
            a[6] = (short)f2bu(a1.z); a[7] = (short)f2bu(a1.w);
#pragma unroll
            for (int j = 0; j < 8; j++) {
                b[j] = (short)f2bu(bp[(kb * 32 + j) * 3072]);
            }
            acc = __builtin_amdgcn_mfma_f32_16x16x32_bf16(a, b, acc, 0, 0, 0);
        }
#pragma unroll
        for (int r = 0; r < 4; r++) {
            int k = mt * 16 + quad * 4 + r;  // gemm2 k index (0..255)
            int off = ((nt * 8 + (k >> 5)) * 64 + ((k >> 3) & 3) * 16 + l15) * 8 + (k & 7);
            vw2frag[off] = f2bu(acc[r] * 0.0625f);  // 1/sqrt(256)
        }
    } else {
        // ---- inc bitmask ----
        int wi = bx - 1552;            // 0..15
        unsigned bits = 0u;
        int base = t * 512 + wi * 32;
#pragma unroll
        for (int b = 0; b < 32; b++) {
            if (inc_w[base + b] > 0.0f) bits |= (1u << b);
        }
        mask[wi * 256 + t] = bits;
    }
}

// ---------------------------------------------------------------------------
// K3: clauses via bitwise AND over logit signs.  One block per (m-tile, quad)
// = 4 rows; 392 blocks.  Thread t = clause n.  float4 loads of D-native
// partials (256B contiguous per 16 lanes); 4 ballots (one per row).
__global__ __launch_bounds__(256) void tm_kernel(const float* __restrict__ part,
                                                 const float* __restrict__ b1,
                                                 const unsigned* __restrict__ mask,
                                                 float* __restrict__ cl_out,
                                                 bf16* __restrict__ clauses_bf,
                                                 float* __restrict__ sum_out) {
    __shared__ unsigned g_s[4][16];   // [row r][word]
    __shared__ float red[4][4];       // [wave][row r]
    int blk = blockIdx.x;             // 0..391
    int mt = blk >> 2;                // m-tile 0..97
    int qm = blk & 3;                 // quad 0..3
    int row0 = mt * 16 + qm * 4;
    int t = threadIdx.x;              // clause n
    int wave = t >> 6;
    int lane = t & 63;

    float bv = b1[t];
    float L0 = bv, L1 = bv, L2 = bv, L3 = bv;
    const float* base = part + ((size_t)(mt * 16 + (t >> 4)) * 64 + qm * 16 + (t & 15)) * 4;
#pragma unroll
    for (int s = 0; s < 8; s++) {
        float4 v = *reinterpret_cast<const float4*>(base + (size_t)s * 401408);
        L0 += v.x; L1 += v.y; L2 += v.z; L3 += v.w;
    }
    float Ls[4] = {L0, L1, L2, L3};
#pragma unroll
    for (int r = 0; r < 4; r++) {
        unsigned long long bhi = __ballot(Ls[r] > 0.0f);  // lit n (positive)
        unsigned long long blo = __ballot(Ls[r] < 0.0f);  // lit 256+n (negated)
        if (lane == 0) {
            g_s[r][wave * 2]         = (unsigned)bhi;
            g_s[r][wave * 2 + 1]     = (unsigned)(bhi >> 32);
            g_s[r][8 + wave * 2]     = (unsigned)blo;
            g_s[r][8 + wave * 2 + 1] = (unsigned)(blo >> 32);
        }
    }
    __syncthreads();
    unsigned ok0 = 1u, ok1 = 1u, ok2 = 1u, ok3 = 1u;
#pragma unroll
    for (int w = 0; w < 16; w++) {
        unsigned mw = mask[w * 256 + t];
        ok0 &= (((~g_s[0][w]) & mw) == 0u) ? 1u : 0u;
        ok1 &= (((~g_s[1][w]) & mw) == 0u) ? 1u : 0u;
        ok2 &= (((~g_s[2][w]) & mw) == 0u) ? 1u : 0u;
        ok3 &= (((~g_s[3][w]) & mw) == 0u) ? 1u : 0u;
    }
    unsigned oks[4] = {ok0, ok1, ok2, ok3};
#pragma unroll
    for (int r = 0; r < 4; r++) {
        float hard = (float)oks[r];
        int idx = (row0 + r) * 256 + t;
        cl_out[idx] = hard;
        clauses_bf[idx] = f2b(hard);
        unsigned long long cb = __ballot(oks[r] != 0u);
        if (lane == 0) red[wave][r] = (float)__popcll(cb);
    }
    __syncthreads();
    if (t < 4) {
        sum_out[row0 + t] =
            (red[0][t] + red[1][t] + red[2][t] + red[3][t]) * (1.0f / 256.0f);
    }
}

// ---------------------------------------------------------------------------
// K4: fused  feat = sigmoid(clauses @ vw2 + b2)  +  window-reverse + roll(+2,+2)
// + gated residual -> out.  M=1568, N=3072, K=256.  grid (49, 24), 4 waves
// 2m x 2n, wave tile 16m x 64n (4 acc tiles).  feat never materialized.
__global__ __launch_bounds__(256) void gemm2_out(const bf16* __restrict__ clauses_bf,
                                                 const unsigned short* __restrict__ vw2frag,
                                                 const float* __restrict__ b2v,
                                                 const float* __restrict__ x,
                                                 const float* __restrict__ gate,
                                                 float* __restrict__ out) {
    int t = threadIdx.x;
    int wave = t >> 6;
    int lane = t & 63;
    int quad = lane >> 4;
    int mlo = lane & 15;
    int wm = wave & 1;
    int wn = wave >> 1;
    int m0 = blockIdx.x * 32 + wm * 16;
    int nb0 = blockIdx.y * 8 + wn * 4;  // 16-wide n-tile base (0..191)

    const bf16* ap = clauses_bf + (m0 + mlo) * 256 + quad * 8;
    const unsigned short* bp = vw2frag + lane * 8;

    floatx4 acc[4];
#pragma unroll
    for (int i = 0; i < 4; i++) acc[i] = (floatx4){0.f, 0.f, 0.f, 0.f};

#pragma unroll
    for (int kb = 0; kb < 8; kb++) {
        short8 a = *reinterpret_cast<const short8*>(ap + kb * 32);
#pragma unroll
        for (int i = 0; i < 4; i++) {
            short8 b = *reinterpret_cast<const short8*>(
                bp + ((size_t)((nb0 + i) * 8 + kb)) * 512);
            acc[i] = __builtin_amdgcn_mfma_f32_16x16x32_bf16(a, b, acc[i], 0, 0, 0);
        }
    }

    float g = sigmoidf_(gate[0]);
    // per-r inverse window mapping: m_g -> (batch, window-h, window-w)
    int bq[4], wh[4], ww[4];
#pragma unroll
    for (int r = 0; r < 4; r++) {
        int m_g = m0 + quad * 4 + r;
        bq[r] = m_g / 196;
        int rem = m_g - bq[r] * 196;
        wh[r] = rem / 14;
        ww[r] = rem - wh[r] * 14;
    }
#pragma unroll
    for (int i = 0; i < 4; i++) {
        int n_g = (nb0 + i) * 16 + mlo;
        int cell = n_g / 192;           // 0..15 (position inside 4x4 window)
        int ch = n_g - cell * 192;      // channel
        int cellh = cell >> 2;
        int cellw = cell & 3;
        float bb = b2v[n_g];
#pragma unroll
        for (int r = 0; r < 4; r++) {
            int hh = wh[r] * 4 + cellh + 2; if (hh >= 56) hh -= 56;  // roll(+2)
            int wc = ww[r] * 4 + cellw + 2; if (wc >= 56) wc -= 56;
            int gid = ((bq[r] * 56 + hh) * 56 + wc) * 192 + ch;
            float mv = sigmoidf_(acc[i][r] + bb);
            out[gid] = x[gid] + g * mv + (1.0f - g) * sigmoidf_(mv);
        }
    }
}

// ---------------------------------------------------------------------------
extern "C" void kernel_launch(void* const* d_in, const int* in_sizes, int n_in,
                              void* d_out, int out_size, void* d_ws, size_t ws_size,
                              hipStream_t stream) {
    const float* x      = (const float*)d_in[0];
    const float* gamma  = (const float*)d_in[1];
    const float* beta   = (const float*)d_in[2];
    const float* W1     = (const float*)d_in[3];
    const float* b1     = (const float*)d_in[4];
    const float* inc_w  = (const float*)d_in[5];
    const float* vote_w = (const float*)d_in[6];
    const float* W2     = (const float*)d_in[7];
    const float* b2v    = (const float*)d_in[8];
    const float* gate   = (const float*)d_in[9];

    char* ws = (char*)d_ws;
    // workspace carve (bytes), total ~26.4 MB:
    bf16*           win        = (bf16*)(ws + 0);                  // 9,633,792
    float*          part       = (float*)(ws + 9633792);           // 12,845,056 (8x 1568*256*4)
    unsigned short* w1frag     = (unsigned short*)(ws + 22478848); // 1,572,864
    unsigned short* vw2frag    = (unsigned short*)(ws + 24051712); // 1,572,864
    bf16*           clauses_bf = (bf16*)(ws + 25624576);           //   802,816
    unsigned*       mask       = (unsigned*)(ws + 26427392);       //    16,384

    float* out     = (float*)d_out;
    float* cl_out  = out + 4816896;            // clauses: 1568*256
    float* sum_out = cl_out + 401408;          // summary: 1568

    k1_lnwin_w1frag<<<6656, 256, 0, stream>>>(x, gamma, beta, W1, win, w1frag);
    k2_gemm1_vw2_mask<<<1568, 256, 0, stream>>>(win, w1frag, vote_w, W2, inc_w,
                                                part, vw2frag, mask);
    tm_kernel<<<392, 256, 0, stream>>>(part, b1, mask, cl_out, clauses_bf, sum_out);
    gemm2_out<<<dim3(49, 24), 256, 0, stream>>>(clauses_bf, vw2frag, b2v, x, gate, out);
}